// Round 3
// baseline (102.317 us; speedup 1.0000x reference)
//
#include <hip/hip_runtime.h>
#include <stdint.h>

// GAT layer: N=4096 nodes, IN=256, H=4 heads, F=64 out/head.
constexpr int NODES = 4096;
constexpr int KIN   = 256;
constexpr int NHEAD = 4;
constexpr int NF    = 64;
constexpr int HFQ   = 256;   // NHEAD*NF
#define SLOPE 0.2f
#define L2E 1.44269504088896340736f

typedef __attribute__((ext_vector_type(8))) short short8;
typedef __attribute__((ext_vector_type(4))) float floatx4;
typedef __attribute__((ext_vector_type(16))) float f32x16;

static __device__ __forceinline__ unsigned short f2bf(float f) {
  return __builtin_bit_cast(unsigned short, (__bf16)f);
}

// ---- kernel 1: fp32 -> bf16 conversion of h and W --------------------------
__global__ __launch_bounds__(256) void prep_kernel(
    const float* __restrict__ hin, const float* __restrict__ Win,
    unsigned short* __restrict__ hB, unsigned short* __restrict__ WB) {
  int idx = blockIdx.x * 256 + threadIdx.x;           // float4 index
  const int NH4 = (NODES * KIN) / 4;                  // 262144
  const int NW4 = (HFQ * KIN) / 4;                    // 16384
  if (idx < NH4) {
    float4 v = reinterpret_cast<const float4*>(hin)[idx];
    ushort4 o = { f2bf(v.x), f2bf(v.y), f2bf(v.z), f2bf(v.w) };
    reinterpret_cast<ushort4*>(hB)[idx] = o;
  } else if (idx < NH4 + NW4) {
    int j = idx - NH4;
    float4 v = reinterpret_cast<const float4*>(Win)[j];
    ushort4 o = { f2bf(v.x), f2bf(v.y), f2bf(v.z), f2bf(v.w) };
    reinterpret_cast<ushort4*>(WB)[j] = o;
  }
}

// ---- kernel 2: projection g = h @ W^T + b  (MFMA 16x16x32 bf16) ------------
// writes g32 [NODES][HFQ] fp32 and gT2 tiled bf16: gT2[jt][c][jj],
// element (node j, feature c) at  (j>>5)*8192 + c*32 + (j&31).
__global__ __launch_bounds__(256) void proj_kernel(
    const unsigned short* __restrict__ hB, const unsigned short* __restrict__ WB,
    const float* __restrict__ bias,
    float* __restrict__ g32, unsigned short* __restrict__ gT2) {
  int wave = threadIdx.x >> 6, lane = threadIdx.x & 63;
  int tile = blockIdx.x * 4 + wave;       // 4096 tiles = 256 mtiles x 16 ntiles
  int mt = tile >> 4, nt = tile & 15;
  int m0 = mt * 16, n0 = nt * 16;
  int r = lane & 15, kg = lane >> 4;
  floatx4 acc = {0.f, 0.f, 0.f, 0.f};
  const short8* Ap = reinterpret_cast<const short8*>(hB + (m0 + r) * KIN + kg * 8);
  const short8* Bp = reinterpret_cast<const short8*>(WB + (n0 + r) * KIN + kg * 8);
#pragma unroll
  for (int kb = 0; kb < 8; ++kb) {
    short8 a = Ap[kb * 4];   // advance 32 shorts per K-step
    short8 b = Bp[kb * 4];
    acc = __builtin_amdgcn_mfma_f32_16x16x32_bf16(a, b, acc, 0, 0, 0);
  }
  int col = n0 + r;
  float bv = bias[col];
#pragma unroll
  for (int q = 0; q < 4; ++q) {
    int row = m0 + kg * 4 + q;            // C/D layout: row=(lane>>4)*4+reg, col=lane&15
    float v = acc[q] + bv;
    g32[row * HFQ + col] = v;
    gT2[(row >> 5) * (HFQ * 32) + col * 32 + (row & 31)] = f2bf(v);
  }
}

// ---- kernel 3: src/dst per (node, head) -> factorized exp terms ------------
// srcP[n][h] = (es1, es2, thr) = (exp(s), exp(0.2s), exp(-s)), s incl. bias
// ed1P[h][n] = exp(d), ed2P[h][n] = exp(0.2d)
__global__ __launch_bounds__(256) void srcdst_kernel(
    const float* __restrict__ g32, const float* __restrict__ attn_w,
    const float* __restrict__ attn_b,
    float4* __restrict__ srcP, float* __restrict__ ed1P, float* __restrict__ ed2P) {
  int wave = threadIdx.x >> 6, lane = threadIdx.x & 63;
  int n = blockIdx.x * 4 + wave;
  float aws = attn_w[lane], awd = attn_w[64 + lane];
  float ab = attn_b[0];
#pragma unroll
  for (int hh = 0; hh < NHEAD; ++hh) {
    float v = g32[n * HFQ + hh * NF + lane];
    float s = v * aws, d = v * awd;
#pragma unroll
    for (int m = 32; m >= 1; m >>= 1) {
      s += __shfl_xor(s, m, 64);
      d += __shfl_xor(d, m, 64);
    }
    if (lane == 0) {
      s += ab;
      float4 sp;
      sp.x = exp2f(s * L2E);
      sp.y = exp2f(0.2f * s * L2E);
      sp.z = exp2f(-s * L2E);
      sp.w = 0.f;
      srcP[n * NHEAD + hh] = sp;
      ed1P[hh * NODES + n] = exp2f(d * L2E);
      ed2P[hh * NODES + n] = exp2f(0.2f * d * L2E);
    }
  }
}

// ---- kernel 4: fused attention, 32x32x16 MFMA, LDS-free, barrier-free ------
// grid (128 row-tiles of 32, NP j-partitions), block 256 = 4 waves (1 head ea).
// D[c][i] = sum_j g[c,j] * w[j,i]:  A = g-tile (from gT2), B = w in-register.
// B layout: n = lane&31 = attn row i, k = 8*(lane>>5)+r = j within chunk.
// w = (ed1 >= thr) ? es1*ed1 : es2*ed2, masked by adj. Denominator via a
// ones-A MFMA (row sums on the matrix pipe).
__global__ __launch_bounds__(256, 4) void attn_kernel(
    const int* __restrict__ adj, const unsigned short* __restrict__ gT2,
    const float4* __restrict__ srcP,
    const float* __restrict__ ed1P, const float* __restrict__ ed2P,
    float* __restrict__ pnum, float* __restrict__ pden, int JP) {
  int tid = threadIdx.x;
  int hh = tid >> 6, lane = tid & 63;
  int il = lane & 31, hi = lane >> 5;
  int part = blockIdx.y, jstart = part * JP;
  int i = blockIdx.x * 32 + il;           // attention row this lane owns

  float4 sp = srcP[i * NHEAD + hh];
  float es1 = sp.x, es2 = sp.y, thr = sp.z;

  f32x16 acc0 = {0.f,0.f,0.f,0.f,0.f,0.f,0.f,0.f,0.f,0.f,0.f,0.f,0.f,0.f,0.f,0.f};
  f32x16 acc1 = acc0, accd = acc0;

  short8 ones;
#pragma unroll
  for (int r = 0; r < 8; ++r) ones[r] = (short)0x3F80;  // bf16 1.0

  const float* e1base = ed1P + hh * NODES;
  const float* e2base = ed2P + hh * NODES;
  const int* adjrow = adj + (size_t)i * NODES;
  const unsigned short* tA0 = gT2 + (hh * 64 + il) * 32 + hi * 8;
  const unsigned short* tA1 = tA0 + 32 * 32;

  int nsteps = JP / 32;
  for (int stp = 0; stp < nsteps; ++stp) {
    int j0 = jstart + stp * 32;
    size_t toff = (size_t)(j0 >> 5) * (HFQ * 32);
#pragma unroll
    for (int ch = 0; ch < 2; ++ch) {
      int jc = j0 + ch * 16 + hi * 8;     // first of this lane's 8 j's
      float4 e1a = *reinterpret_cast<const float4*>(e1base + jc);
      float4 e1b = *reinterpret_cast<const float4*>(e1base + jc + 4);
      float4 e2a = *reinterpret_cast<const float4*>(e2base + jc);
      float4 e2b = *reinterpret_cast<const float4*>(e2base + jc + 4);
      int4 aa = *reinterpret_cast<const int4*>(adjrow + jc);
      int4 ab4 = *reinterpret_cast<const int4*>(adjrow + jc + 4);
      float e1v[8] = {e1a.x, e1a.y, e1a.z, e1a.w, e1b.x, e1b.y, e1b.z, e1b.w};
      float e2v[8] = {e2a.x, e2a.y, e2a.z, e2a.w, e2b.x, e2b.y, e2b.z, e2b.w};
      int   av [8] = {aa.x, aa.y, aa.z, aa.w, ab4.x, ab4.y, ab4.z, ab4.w};
      short8 bfr;
#pragma unroll
      for (int r = 0; r < 8; ++r) {
        bool sel = e1v[r] >= thr;
        float w = (sel ? es1 : es2) * (sel ? e1v[r] : e2v[r]);
        w = (av[r] != 0) ? w : 0.f;
        bfr[r] = (short)f2bf(w);
      }
      const short8 a0 = *reinterpret_cast<const short8*>(tA0 + toff + ch * 16);
      const short8 a1 = *reinterpret_cast<const short8*>(tA1 + toff + ch * 16);
      acc0 = __builtin_amdgcn_mfma_f32_32x32x16_bf16(a0, bfr, acc0, 0, 0, 0);
      acc1 = __builtin_amdgcn_mfma_f32_32x32x16_bf16(a1, bfr, acc1, 0, 0, 0);
      accd = __builtin_amdgcn_mfma_f32_32x32x16_bf16(ones, bfr, accd, 0, 0, 0);
    }
  }

  // denominator: all rows of accd identical; col = il
  if (hi == 0)
    pden[(size_t)part * (NODES * NHEAD) + i * NHEAD + hh] = accd[0];

  // numerator: C layout col=lane&31 (=i), row c = (reg&3)+8*(reg>>2)+4*hi
  float* pbase = pnum + (size_t)part * (NODES * HFQ) + (size_t)i * HFQ + hh * NF;
#pragma unroll
  for (int reg = 0; reg < 16; ++reg) {
    int crow = (reg & 3) + 8 * (reg >> 2) + 4 * hi;
    pbase[crow] = acc0[reg];
    pbase[32 + crow] = acc1[reg];
  }
}

// ---- kernel 5: combine partials, normalize, mean over heads ----------------
__global__ __launch_bounds__(256) void combine_kernel(
    const float* __restrict__ pnum, const float* __restrict__ pden,
    float* __restrict__ out, int NP) {
  int idx = blockIdx.x * 256 + threadIdx.x;
  int i = idx >> 6, f = idx & 63;
  float o = 0.f;
#pragma unroll
  for (int hh = 0; hh < NHEAD; ++hh) {
    float num = 0.f, den = 0.f;
    for (int p = 0; p < NP; ++p) {
      num += pnum[p * (NODES * HFQ) + i * HFQ + hh * NF + f];
      den += pden[p * (NODES * NHEAD) + i * NHEAD + hh];
    }
    o += num / den;
  }
  out[idx] = 0.25f * o;
}

extern "C" void kernel_launch(void* const* d_in, const int* in_sizes, int n_in,
                              void* d_out, int out_size, void* d_ws, size_t ws_size,
                              hipStream_t stream) {
  const float* hin = (const float*)d_in[0];
  const int* adj   = (const int*)d_in[1];
  const float* W   = (const float*)d_in[2];
  const float* b   = (const float*)d_in[3];
  const float* aw  = (const float*)d_in[4];
  const float* ab  = (const float*)d_in[5];
  float* out = (float*)d_out;
  char* ws = (char*)d_ws;

  unsigned short* hB  = (unsigned short*)(ws + 0x000000);  // 2 MB
  unsigned short* WB  = (unsigned short*)(ws + 0x200000);  // 128 KB
  float* g32          = (float*)(ws + 0x400000);           // 4 MB
  unsigned short* gT2 = (unsigned short*)(ws + 0x800000);  // 2 MB (tiled)
  float4* srcP        = (float4*)(ws + 0xA00000);          // 256 KB
  float* ed1P         = (float*)(ws + 0xA40000);           // 64 KB
  float* ed2P         = (float*)(ws + 0xA50000);           // 64 KB
  float* pden         = (float*)(ws + 0xA60000);           // up to 512 KB
  float* pnum         = (float*)(ws + 0xB00000);           // NP * 4 MB
  const size_t base = 0xB00000;

  int NP = 2;
  if (ws_size >= base + 8ull * NODES * HFQ * 4) NP = 8;
  else if (ws_size >= base + 4ull * NODES * HFQ * 4) NP = 4;
  int JP = NODES / NP;

  prep_kernel<<<1088, 256, 0, stream>>>(hin, W, hB, WB);
  proj_kernel<<<1024, 256, 0, stream>>>(hB, WB, b, g32, gT2);
  srcdst_kernel<<<1024, 256, 0, stream>>>(g32, aw, ab, srcP, ed1P, ed2P);
  attn_kernel<<<dim3(128, NP), 256, 0, stream>>>(adj, gT2, srcP, ed1P, ed2P, pnum, pden, JP);
  combine_kernel<<<1024, 256, 0, stream>>>(pnum, pden, out, NP);
}